// Round 17
// baseline (138.438 us; speedup 1.0000x reference)
//
#include <hip/hip_runtime.h>
#include <hip/hip_bf16.h>

#define N_SRC_N  100000
#define N_DST_N  50000
#define NE       1000000
#define IN_F     256
#define NH       4
#define ND       32
#define HD       128   // NH*ND
#define NEG_SLOPE 0.2f

#define DPB      32          // dsts per bucket (DPB16 regressed: per-block overhead)
#define NB       1563        // ceil(50000/32)
#define CAP      1024        // LDS edge cap per bucket (mean 640, sd 25 -> +15 sigma)

typedef __attribute__((ext_vector_type(8))) short short8v;
typedef __attribute__((ext_vector_type(4))) short short4v;
typedef __attribute__((ext_vector_type(4))) float f32x4;

__device__ __forceinline__ short f2bf(float f) {
    __hip_bfloat16 h = __float2bfloat16(f);
    return *reinterpret_cast<short*>(&h);
}
__device__ __forceinline__ float bflo(unsigned u) { return __uint_as_float(u << 16); }
__device__ __forceinline__ float bfhi(unsigned u) { return __uint_as_float(u & 0xffff0000u); }

// ---------------- convert fc_w fp32 -> bf16 -----------------------------------------
__global__ __launch_bounds__(256) void cvt_w(const float* __restrict__ w,
                                             short* __restrict__ wb)
{
    int i4 = blockIdx.x * 256 + threadIdx.x;
    if (i4 < (HD * IN_F) / 4) {
        f32x4 v = ((const f32x4*)w)[i4];
        short4v s;
        s[0] = f2bf(v[0]); s[1] = f2bf(v[1]); s[2] = f2bf(v[2]); s[3] = f2bf(v[3]);
        ((short4v*)wb)[i4] = s;
    }
}

// ---------------- MFMA GEMM: hb = bf16(x @ w^T), el fused; hist fused in tail -------
// R14-proven core: 512 blocks x 512 threads (16 waves/CU), W (64KB bf16) in LDS
// (swizzled), A global->VGPR read-exactly-once. Tail reuses wlds as hist scratch.
__global__ __launch_bounds__(512, 4) void gemm_fc_mfma(
    const float* __restrict__ x, const short* __restrict__ wb,
    const float* __restrict__ al, short* __restrict__ hb,
    float* __restrict__ el, const int4* __restrict__ dst4,
    int* __restrict__ bcnt)
{
    __shared__ short wlds[HD * IN_F];    // 64KB: 128 rows x 512B, swizzled

    const int tid = threadIdx.x;
    {
        int row = tid >> 2, qt = tid & 3;
#pragma unroll
        for (int c = 0; c < 8; ++c) {
            int chunk = qt * 8 + c;                         // 0..31
            short8v v = *(const short8v*)(wb + row * IN_F + chunk * 8);
            int boff = (chunk * 16) ^ ((row & 7) << 4);     // bijective swizzle
            *(short8v*)((char*)wlds + row * 512 + boff) = v;
        }
    }
    __syncthreads();

    const int w  = tid >> 6;   // 0..7
    const int l  = tid & 63;
    const int lr = l & 15;
    const int lk = l >> 4;

    float alv[8];
#pragma unroll
    for (int ct = 0; ct < 8; ++ct) alv[ct] = al[ct * 16 + lr];

    const int wave_id = blockIdx.x * 8 + w;
    for (int tile = wave_id; tile < N_SRC_N / 16; tile += 4096) {
        const int row0 = tile * 16;
        const float* xp = x + (size_t)(row0 + lr) * IN_F + lk * 8;

        f32x4 a[16];
#pragma unroll
        for (int kk = 0; kk < 8; ++kk) {
            a[2 * kk]     = *(const f32x4*)(xp + kk * 32);
            a[2 * kk + 1] = *(const f32x4*)(xp + kk * 32 + 4);
        }
        __builtin_amdgcn_sched_barrier(0);   // all 16 A-loads issued before compute

        f32x4 acc[8];
#pragma unroll
        for (int ct = 0; ct < 8; ++ct) acc[ct] = (f32x4){0.f, 0.f, 0.f, 0.f};

#pragma unroll
        for (int kk = 0; kk < 8; ++kk) {
            f32x4 u0 = a[2 * kk], u1 = a[2 * kk + 1];
            short8v af;
            af[0] = f2bf(u0[0]); af[1] = f2bf(u0[1]);
            af[2] = f2bf(u0[2]); af[3] = f2bf(u0[3]);
            af[4] = f2bf(u1[0]); af[5] = f2bf(u1[1]);
            af[6] = f2bf(u1[2]); af[7] = f2bf(u1[3]);
            const int boff = (kk * 64 + lk * 16) ^ ((lr & 7) << 4);
#pragma unroll
            for (int ct = 0; ct < 8; ++ct) {
                short8v bf = *(const short8v*)((const char*)wlds
                                               + (ct * 16 + lr) * 512 + boff);
                acc[ct] = __builtin_amdgcn_mfma_f32_16x16x32_bf16(af, bf, acc[ct], 0, 0, 0);
            }
        }

#pragma unroll
        for (int r = 0; r < 4; ++r) {
            short* hp = hb + (size_t)(row0 + lk * 4 + r) * HD + lr;
#pragma unroll
            for (int ct = 0; ct < 8; ++ct) hp[ct * 16] = f2bf(acc[ct][r]);
        }

#pragma unroll
        for (int h = 0; h < 4; ++h) {
            float p[4];
#pragma unroll
            for (int r = 0; r < 4; ++r)
                p[r] = acc[2 * h][r] * alv[2 * h] + acc[2 * h + 1][r] * alv[2 * h + 1];
#pragma unroll
            for (int o = 1; o < 16; o <<= 1) {
#pragma unroll
                for (int r = 0; r < 4; ++r) p[r] += __shfl_xor(p[r], o, 64);
            }
            if (lr == 0) {
#pragma unroll
                for (int r = 0; r < 4; ++r)
                    el[(row0 + lk * 4 + r) * NH + h] = p[r];
            }
        }
    }

    // -------- fused bucket hist (reuse wlds as int scratch; gemm loop is done) -----
    __syncthreads();
    int* lhist = (int*)wlds;
    for (int i = tid; i < NB; i += 512) lhist[i] = 0;
    __syncthreads();
    int e4 = blockIdx.x * 512 + tid;              // 512 x 512 = 262144 = NE/4 exactly
    if (e4 < NE / 4) {
        int4 v = dst4[e4];
        atomicAdd(&lhist[v.x >> 5], 1); atomicAdd(&lhist[v.y >> 5], 1);
        atomicAdd(&lhist[v.z >> 5], 1); atomicAdd(&lhist[v.w >> 5], 1);
    }
    __syncthreads();
    for (int i = tid; i < NB; i += 512) {
        int c = lhist[i];
        if (c > 0) atomicAdd(&bcnt[i], c);
    }
}

// -------- exclusive scan of bcnt[NB] ------------------------------------------------
__global__ __launch_bounds__(1024) void bucket_scan(
    const int* __restrict__ bcnt, int* __restrict__ boff, int* __restrict__ bcur, int n)
{
    int tid = threadIdx.x;
    int i0 = 2 * tid, i1 = 2 * tid + 1;
    int a = (i0 < n) ? bcnt[i0] : 0;
    int c = (i1 < n) ? bcnt[i1] : 0;
    int s = a + c, v = s;
#pragma unroll
    for (int o = 1; o < 64; o <<= 1) {
        int t = __shfl_up(v, o, 64);
        if ((tid & 63) >= o) v += t;
    }
    __shared__ int ws[16];
    if ((tid & 63) == 63) ws[tid >> 6] = v;
    __syncthreads();
    int add = 0;
    for (int q = 0; q < (tid >> 6); ++q) add += ws[q];
    int excl = v - s + add;
    if (i0 < n) { boff[i0] = excl;     bcur[i0] = excl; }
    if (i1 < n) { boff[i1] = excl + a; bcur[i1] = excl + a; }
}

// -------- partition edges into bucket-segmented ebuf (packed src | dstlocal<<17) ----
__global__ __launch_bounds__(256) void partition(
    const int4* __restrict__ src4, const int4* __restrict__ dst4,
    int* __restrict__ bcur, int* __restrict__ ebuf, int n4)
{
    __shared__ int lh[NB];
    __shared__ int base[NB];
    for (int i = threadIdx.x; i < NB; i += 256) lh[i] = 0;
    __syncthreads();
    int4 sv[8], dv[8];
#pragma unroll
    for (int q = 0; q < 8; ++q) {
        int e4 = blockIdx.x * 2048 + q * 256 + threadIdx.x;
        if (e4 < n4) {
            sv[q] = src4[e4]; dv[q] = dst4[e4];
            atomicAdd(&lh[dv[q].x >> 5], 1); atomicAdd(&lh[dv[q].y >> 5], 1);
            atomicAdd(&lh[dv[q].z >> 5], 1); atomicAdd(&lh[dv[q].w >> 5], 1);
        } else {
            dv[q].x = -1;
        }
    }
    __syncthreads();
    for (int i = threadIdx.x; i < NB; i += 256) {
        int cnt = lh[i];
        base[i] = (cnt > 0) ? atomicAdd(&bcur[i], cnt) : 0;
        lh[i] = 0;
    }
    __syncthreads();
#pragma unroll
    for (int q = 0; q < 8; ++q) {
        if (dv[q].x < 0) continue;
        int ss[4] = {sv[q].x, sv[q].y, sv[q].z, sv[q].w};
        int dd[4] = {dv[q].x, dv[q].y, dv[q].z, dv[q].w};
#pragma unroll
        for (int j = 0; j < 4; ++j) {
            int b = dd[j] >> 5;
            int off = atomicAdd(&lh[b], 1);
            ebuf[base[b] + off] = ss[j] | ((dd[j] & 31) << 17);
        }
    }
}

// -------- fused LDS counting-sort + gather + inline er (R12 structure) --------------
// 16-edge batches: 32 independent loads in flight per wave before the exp/FMA block.
__global__ __launch_bounds__(256) void gat_gather(
    const short* __restrict__ hb, const float* __restrict__ el,
    const float* __restrict__ ar, const int* __restrict__ dnid,
    const int* __restrict__ ebuf, const int* __restrict__ bcnt,
    const int* __restrict__ boff, float* __restrict__ out, int ndst)
{
    __shared__ int stage_[CAP];
    __shared__ int ssrc[CAP];
    __shared__ int lh[DPB];
    __shared__ int loff[DPB + 1];
    __shared__ int curs[DPB];

    const int b = blockIdx.x;
    const int tid = threadIdx.x;
    const int cnt = bcnt[b];
    const int gbase = boff[b];
    const int lcnt = (cnt < CAP) ? cnt : CAP;

    if (tid < DPB) lh[tid] = 0;
    __syncthreads();
    for (int i = tid; i < lcnt; i += 256) {
        int p = ebuf[gbase + i];
        stage_[i] = p;
        atomicAdd(&lh[(p >> 17) & 31], 1);
    }
    __syncthreads();
    if (tid < DPB) {
        int v = lh[tid];
#pragma unroll
        for (int o = 1; o < 32; o <<= 1) {
            int t = __shfl_up(v, o, 64);
            if (tid >= o) v += t;
        }
        loff[tid + 1] = v;
        if (tid == 0) loff[0] = 0;
    }
    __syncthreads();
    if (tid < DPB) curs[tid] = loff[tid];
    __syncthreads();
    for (int i = tid; i < lcnt; i += 256) {
        int p = stage_[i];
        int dl = (p >> 17) & 31;
        int pos = atomicAdd(&curs[dl], 1);
        ssrc[pos] = (p & 0x1FFFF) << 8;        // pre-scaled hb byte offset
    }
    __syncthreads();

    const int wv = tid >> 6;
    const int l  = tid & 63;
    const int head = l >> 4;
    const char* hbase = (const char*)hb + 4 * l;       // lane byte base into hb row
    const char* ebase = (const char*)el + head * 4;    // head byte base into el row
    const float ar0 = ar[2 * l], ar1 = ar[2 * l + 1];

    for (int dl = wv; dl < DPB; dl += 4) {
        int d = b * DPB + dl;
        if (d >= ndst) continue;
        int j0 = loff[dl], j1 = loff[dl + 1];

        // inline er[d, head]: dot(hb[dnid[d]], ar) reduced over the 16-lane head group
        int nid = dnid[d];
        unsigned ue = *(const unsigned*)(hbase + (size_t)nid * 256);
        float erv = bflo(ue) * ar0 + bfhi(ue) * ar1;
#pragma unroll
        for (int o = 1; o < 16; o <<= 1) erv += __shfl_xor(erv, o, 64);

        float sumA = 0.f, sumB = 0.f;
        float acc0A = 0.f, acc1A = 0.f, acc0B = 0.f, acc1B = 0.f;
        int j = j0;
        // 16-edge batches: 32 independent loads issued before the exp/FMA block
        for (; j + 16 <= j1; j += 16) {
            int off[16]; unsigned u[16]; float ev[16];
#pragma unroll
            for (int q = 0; q < 16; ++q) off[q] = ssrc[j + q];
#pragma unroll
            for (int q = 0; q < 16; ++q)
                u[q] = *(const unsigned*)(hbase + off[q]);
#pragma unroll
            for (int q = 0; q < 16; ++q)
                ev[q] = *(const float*)(ebase + (off[q] >> 4));
#pragma unroll
            for (int q = 0; q < 16; ++q) {
                float e = ev[q] + erv;
                e = fmaxf(e, NEG_SLOPE * e);
                float wq = __expf(e);
                if (q & 1) {
                    sumB += wq;
                    acc0B = fmaf(wq, bflo(u[q]), acc0B);
                    acc1B = fmaf(wq, bfhi(u[q]), acc1B);
                } else {
                    sumA += wq;
                    acc0A = fmaf(wq, bflo(u[q]), acc0A);
                    acc1A = fmaf(wq, bfhi(u[q]), acc1A);
                }
            }
        }
        for (; j + 8 <= j1; j += 8) {
            int off[8]; unsigned u[8]; float ev[8];
#pragma unroll
            for (int q = 0; q < 8; ++q) off[q] = ssrc[j + q];
#pragma unroll
            for (int q = 0; q < 8; ++q)
                u[q] = *(const unsigned*)(hbase + off[q]);
#pragma unroll
            for (int q = 0; q < 8; ++q)
                ev[q] = *(const float*)(ebase + (off[q] >> 4));
#pragma unroll
            for (int q = 0; q < 8; ++q) {
                float e = ev[q] + erv;
                e = fmaxf(e, NEG_SLOPE * e);
                float wq = __expf(e);
                if (q & 1) {
                    sumB += wq;
                    acc0B = fmaf(wq, bflo(u[q]), acc0B);
                    acc1B = fmaf(wq, bfhi(u[q]), acc1B);
                } else {
                    sumA += wq;
                    acc0A = fmaf(wq, bflo(u[q]), acc0A);
                    acc1A = fmaf(wq, bfhi(u[q]), acc1A);
                }
            }
        }
        for (; j < j1; ++j) {
            int off0 = ssrc[j];
            unsigned u0 = *(const unsigned*)(hbase + off0);
            float e0 = *(const float*)(ebase + (off0 >> 4)) + erv;
            e0 = fmaxf(e0, NEG_SLOPE * e0);
            float w0 = __expf(e0);
            sumA += w0;
            acc0A = fmaf(w0, bflo(u0), acc0A); acc1A = fmaf(w0, bfhi(u0), acc1A);
        }
        if (cnt > CAP) {                          // never-taken correctness guard
            for (int t = CAP; t < cnt; ++t) {
                int p = ebuf[gbase + t];
                if (((p >> 17) & 31) == dl) {
                    int off0 = (p & 0x1FFFF) << 8;
                    unsigned u0 = *(const unsigned*)(hbase + off0);
                    float e0 = *(const float*)(ebase + (off0 >> 4)) + erv;
                    e0 = fmaxf(e0, NEG_SLOPE * e0);
                    float w0 = __expf(e0);
                    sumA += w0;
                    acc0A = fmaf(w0, bflo(u0), acc0A); acc1A = fmaf(w0, bfhi(u0), acc1A);
                }
            }
        }
        float sum = sumA + sumB;
        bool any = (j1 > j0) || (cnt > CAP);
        float inv = any ? 1.f / sum : 0.f;
        float2 o2 = make_float2((acc0A + acc0B) * inv, (acc1A + acc1B) * inv);
        *(float2*)(out + (size_t)d * HD + 2 * l) = o2;
    }
}

// -----------------------------------------------------------------------------------
extern "C" void kernel_launch(void* const* d_in, const int* in_sizes, int n_in,
                              void* d_out, int out_size, void* d_ws, size_t ws_size,
                              hipStream_t stream)
{
    const float* x   = (const float*)d_in[0];
    const float* fw  = (const float*)d_in[1];
    const float* al  = (const float*)d_in[2];
    const float* ar  = (const float*)d_in[3];
    const int*   src = (const int*)d_in[4];
    const int*   dst = (const int*)d_in[5];
    const int*   dnid= (const int*)d_in[6];
    float* out = (float*)d_out;

    char* ws = (char*)d_ws;
    size_t off = 0;
    auto alloc = [&](size_t bytes) -> void* {
        void* p = ws + off;
        off = (off + bytes + 255) & ~(size_t)255;
        return p;
    };
    short* hb   = (short*)alloc((size_t)N_SRC_N * HD * sizeof(short));   // 25.6 MB
    short* wb   = (short*)alloc((size_t)HD * IN_F * sizeof(short));      // 64 KB
    float* el   = (float*)alloc((size_t)N_SRC_N * NH * sizeof(float));   // 1.6 MB
    int*   ebuf = (int*)alloc((size_t)NE * sizeof(int));                 // 4 MB
    int*   bcnt = (int*)alloc((size_t)NB * sizeof(int));
    int*   boff = (int*)alloc((size_t)NB * sizeof(int));
    int*   bcur = (int*)alloc((size_t)NB * sizeof(int));

    hipMemsetAsync(bcnt, 0, (size_t)NB * sizeof(int), stream);

    cvt_w<<<(HD * IN_F / 4 + 255) / 256, 256, 0, stream>>>(fw, wb);
    gemm_fc_mfma<<<512, 512, 0, stream>>>(x, wb, al, hb, el, (const int4*)dst, bcnt);
    bucket_scan<<<1, 1024, 0, stream>>>(bcnt, boff, bcur, NB);
    partition<<<(NE / 4 + 2047) / 2048, 256, 0, stream>>>((const int4*)src, (const int4*)dst,
                                                          bcur, ebuf, NE / 4);
    gat_gather<<<NB, 256, 0, stream>>>(hb, el, ar, dnid, ebuf, bcnt, boff, out, N_DST_N);
}

// Round 18
// 121.051 us; speedup vs baseline: 1.1436x; 1.1436x over previous
//
#include <hip/hip_runtime.h>
#include <hip/hip_bf16.h>

#define N_SRC_N  100000
#define N_DST_N  50000
#define NE       1000000
#define IN_F     256
#define NH       4
#define ND       32
#define HD       128   // NH*ND
#define NEG_SLOPE 0.2f

#define DPB      32          // dsts per bucket
#define NB       1563        // ceil(50000/32)
#define CAP      1024        // LDS edge cap per bucket (mean 640, sd 25 -> +15 sigma)

#define NTILE    (N_SRC_N / 16)   // 6250
#define NWAVES   2048             // 512 blocks x 4 waves

typedef __attribute__((ext_vector_type(8))) short short8v;
typedef __attribute__((ext_vector_type(4))) short short4v;
typedef __attribute__((ext_vector_type(4))) float f32x4;

__device__ __forceinline__ short f2bf(float f) {
    __hip_bfloat16 h = __float2bfloat16(f);
    return *reinterpret_cast<short*>(&h);
}
__device__ __forceinline__ float bflo(unsigned u) { return __uint_as_float(u << 16); }
__device__ __forceinline__ float bfhi(unsigned u) { return __uint_as_float(u & 0xffff0000u); }

// ---------------- convert fc_w fp32 -> bf16 -----------------------------------------
__global__ __launch_bounds__(256) void cvt_w(const float* __restrict__ w,
                                             short* __restrict__ wb)
{
    int i4 = blockIdx.x * 256 + threadIdx.x;
    if (i4 < (HD * IN_F) / 4) {
        f32x4 v = ((const f32x4*)w)[i4];
        short4v s;
        s[0] = f2bf(v[0]); s[1] = f2bf(v[1]); s[2] = f2bf(v[2]); s[3] = f2bf(v[3]);
        ((short4v*)wb)[i4] = s;
    }
}

// ---------------- MFMA GEMM: hb = bf16(x @ w^T), el fused; hist fused in tail -------
// R15 configuration (best measured total, 121.4us): register-double-buffered A,
// launch_bounds(256,2); W (64KB bf16) in LDS (swizzled), read b128.
__global__ __launch_bounds__(256, 2) void gemm_fc_mfma(
    const float* __restrict__ x, const short* __restrict__ wb,
    const float* __restrict__ al, short* __restrict__ hb,
    float* __restrict__ el, const int4* __restrict__ dst4,
    int* __restrict__ bcnt)
{
    __shared__ short wlds[HD * IN_F];    // 64KB: 128 rows x 512B, swizzled

    const int tid = threadIdx.x;
    {   // stage W: thread t -> row t>>1, half t&1; 16 chunks of 16B => full 512B row
        int row = tid >> 1, half = tid & 1;
#pragma unroll
        for (int c = 0; c < 16; ++c) {
            int chunk = half * 16 + c;                      // 0..31
            short8v v = *(const short8v*)(wb + row * IN_F + chunk * 8);
            int boff = (chunk * 16) ^ ((row & 7) << 4);     // bijective swizzle
            *(short8v*)((char*)wlds + row * 512 + boff) = v;
        }
    }
    __syncthreads();

    const int w  = tid >> 6;   // 0..3
    const int l  = tid & 63;
    const int lr = l & 15;
    const int lk = l >> 4;

    float alv[8];
#pragma unroll
    for (int ct = 0; ct < 8; ++ct) alv[ct] = al[ct * 16 + lr];

    const int wave_id = blockIdx.x * 4 + w;

    f32x4 aA[16], aB[16];

    auto LOADA = [&](f32x4 (&dst)[16], int tile) {
        const float* xp = x + (size_t)(tile * 16 + lr) * IN_F + lk * 8;
#pragma unroll
        for (int kk = 0; kk < 8; ++kk) {
            dst[2 * kk]     = *(const f32x4*)(xp + kk * 32);
            dst[2 * kk + 1] = *(const f32x4*)(xp + kk * 32 + 4);
        }
    };

    auto COMPUTE = [&](f32x4 (&a)[16], int tile) {
        const int row0 = tile * 16;
        f32x4 acc[8];
#pragma unroll
        for (int ct = 0; ct < 8; ++ct) acc[ct] = (f32x4){0.f, 0.f, 0.f, 0.f};
#pragma unroll
        for (int kk = 0; kk < 8; ++kk) {
            f32x4 u0 = a[2 * kk], u1 = a[2 * kk + 1];
            short8v af;
            af[0] = f2bf(u0[0]); af[1] = f2bf(u0[1]);
            af[2] = f2bf(u0[2]); af[3] = f2bf(u0[3]);
            af[4] = f2bf(u1[0]); af[5] = f2bf(u1[1]);
            af[6] = f2bf(u1[2]); af[7] = f2bf(u1[3]);
            const int boff = (kk * 64 + lk * 16) ^ ((lr & 7) << 4);
#pragma unroll
            for (int ct = 0; ct < 8; ++ct) {
                short8v bf = *(const short8v*)((const char*)wlds
                                               + (ct * 16 + lr) * 512 + boff);
                acc[ct] = __builtin_amdgcn_mfma_f32_16x16x32_bf16(af, bf, acc[ct], 0, 0, 0);
            }
        }
#pragma unroll
        for (int r = 0; r < 4; ++r) {
            short* hp = hb + (size_t)(row0 + lk * 4 + r) * HD + lr;
#pragma unroll
            for (int ct = 0; ct < 8; ++ct) hp[ct * 16] = f2bf(acc[ct][r]);
        }
#pragma unroll
        for (int h = 0; h < 4; ++h) {
            float p[4];
#pragma unroll
            for (int r = 0; r < 4; ++r)
                p[r] = acc[2 * h][r] * alv[2 * h] + acc[2 * h + 1][r] * alv[2 * h + 1];
#pragma unroll
            for (int o = 1; o < 16; o <<= 1) {
#pragma unroll
                for (int r = 0; r < 4; ++r) p[r] += __shfl_xor(p[r], o, 64);
            }
            if (lr == 0) {
#pragma unroll
                for (int r = 0; r < 4; ++r)
                    el[(row0 + lk * 4 + r) * NH + h] = p[r];
            }
        }
    };

    // rolling 2-deep pipeline: next tile's loads issue before current tile's compute
    if (wave_id < NTILE) LOADA(aA, wave_id);
    for (int t = wave_id; t < NTILE; t += 2 * NWAVES) {
        int tB = t + NWAVES;
        if (tB < NTILE) LOADA(aB, tB);
        __builtin_amdgcn_sched_barrier(0);
        COMPUTE(aA, t);
        int tA2 = t + 2 * NWAVES;
        if (tA2 < NTILE) LOADA(aA, tA2);
        __builtin_amdgcn_sched_barrier(0);
        if (tB < NTILE) COMPUTE(aB, tB);
    }

    // -------- fused bucket hist (reuse wlds as int scratch; gemm loop is done) -----
    __syncthreads();
    int* lhist = (int*)wlds;
    for (int i = tid; i < NB; i += 256) lhist[i] = 0;
    __syncthreads();
    for (int e4 = blockIdx.x * 256 + tid; e4 < NE / 4; e4 += 512 * 256) {
        int4 v = dst4[e4];
        atomicAdd(&lhist[v.x >> 5], 1); atomicAdd(&lhist[v.y >> 5], 1);
        atomicAdd(&lhist[v.z >> 5], 1); atomicAdd(&lhist[v.w >> 5], 1);
    }
    __syncthreads();
    for (int i = tid; i < NB; i += 256) {
        int c = lhist[i];
        if (c > 0) atomicAdd(&bcnt[i], c);
    }
}

// -------- exclusive scan of bcnt[NB] ------------------------------------------------
__global__ __launch_bounds__(1024) void bucket_scan(
    const int* __restrict__ bcnt, int* __restrict__ boff, int* __restrict__ bcur, int n)
{
    int tid = threadIdx.x;
    int i0 = 2 * tid, i1 = 2 * tid + 1;
    int a = (i0 < n) ? bcnt[i0] : 0;
    int c = (i1 < n) ? bcnt[i1] : 0;
    int s = a + c, v = s;
#pragma unroll
    for (int o = 1; o < 64; o <<= 1) {
        int t = __shfl_up(v, o, 64);
        if ((tid & 63) >= o) v += t;
    }
    __shared__ int ws[16];
    if ((tid & 63) == 63) ws[tid >> 6] = v;
    __syncthreads();
    int add = 0;
    for (int q = 0; q < (tid >> 6); ++q) add += ws[q];
    int excl = v - s + add;
    if (i0 < n) { boff[i0] = excl;     bcur[i0] = excl; }
    if (i1 < n) { boff[i1] = excl + a; bcur[i1] = excl + a; }
}

// -------- partition edges into bucket-segmented ebuf (packed src | dstlocal<<17) ----
__global__ __launch_bounds__(256) void partition(
    const int4* __restrict__ src4, const int4* __restrict__ dst4,
    int* __restrict__ bcur, int* __restrict__ ebuf, int n4)
{
    __shared__ int lh[NB];
    __shared__ int base[NB];
    for (int i = threadIdx.x; i < NB; i += 256) lh[i] = 0;
    __syncthreads();
    int4 sv[8], dv[8];
#pragma unroll
    for (int q = 0; q < 8; ++q) {
        int e4 = blockIdx.x * 2048 + q * 256 + threadIdx.x;
        if (e4 < n4) {
            sv[q] = src4[e4]; dv[q] = dst4[e4];
            atomicAdd(&lh[dv[q].x >> 5], 1); atomicAdd(&lh[dv[q].y >> 5], 1);
            atomicAdd(&lh[dv[q].z >> 5], 1); atomicAdd(&lh[dv[q].w >> 5], 1);
        } else {
            dv[q].x = -1;
        }
    }
    __syncthreads();
    for (int i = threadIdx.x; i < NB; i += 256) {
        int cnt = lh[i];
        base[i] = (cnt > 0) ? atomicAdd(&bcur[i], cnt) : 0;
        lh[i] = 0;
    }
    __syncthreads();
#pragma unroll
    for (int q = 0; q < 8; ++q) {
        if (dv[q].x < 0) continue;
        int ss[4] = {sv[q].x, sv[q].y, sv[q].z, sv[q].w};
        int dd[4] = {dv[q].x, dv[q].y, dv[q].z, dv[q].w};
#pragma unroll
        for (int j = 0; j < 4; ++j) {
            int b = dd[j] >> 5;
            int off = atomicAdd(&lh[b], 1);
            ebuf[base[b] + off] = ss[j] | ((dd[j] & 31) << 17);
        }
    }
}

// -------- fused LDS counting-sort + gather + inline er (R12-proven, unchanged) ------
__global__ __launch_bounds__(256) void gat_gather(
    const short* __restrict__ hb, const float* __restrict__ el,
    const float* __restrict__ ar, const int* __restrict__ dnid,
    const int* __restrict__ ebuf, const int* __restrict__ bcnt,
    const int* __restrict__ boff, float* __restrict__ out, int ndst)
{
    __shared__ int stage_[CAP];
    __shared__ int ssrc[CAP];
    __shared__ int lh[DPB];
    __shared__ int loff[DPB + 1];
    __shared__ int curs[DPB];

    const int b = blockIdx.x;
    const int tid = threadIdx.x;
    const int cnt = bcnt[b];
    const int gbase = boff[b];
    const int lcnt = (cnt < CAP) ? cnt : CAP;

    if (tid < DPB) lh[tid] = 0;
    __syncthreads();
    for (int i = tid; i < lcnt; i += 256) {
        int p = ebuf[gbase + i];
        stage_[i] = p;
        atomicAdd(&lh[(p >> 17) & 31], 1);
    }
    __syncthreads();
    if (tid < DPB) {
        int v = lh[tid];
#pragma unroll
        for (int o = 1; o < 32; o <<= 1) {
            int t = __shfl_up(v, o, 64);
            if (tid >= o) v += t;
        }
        loff[tid + 1] = v;
        if (tid == 0) loff[0] = 0;
    }
    __syncthreads();
    if (tid < DPB) curs[tid] = loff[tid];
    __syncthreads();
    for (int i = tid; i < lcnt; i += 256) {
        int p = stage_[i];
        int dl = (p >> 17) & 31;
        int pos = atomicAdd(&curs[dl], 1);
        ssrc[pos] = (p & 0x1FFFF) << 8;        // pre-scaled hb byte offset
    }
    __syncthreads();

    const int wv = tid >> 6;
    const int l  = tid & 63;
    const int head = l >> 4;
    const char* hbase = (const char*)hb + 4 * l;       // lane byte base into hb row
    const char* ebase = (const char*)el + head * 4;    // head byte base into el row
    const float ar0 = ar[2 * l], ar1 = ar[2 * l + 1];

    for (int dl = wv; dl < DPB; dl += 4) {
        int d = b * DPB + dl;
        if (d >= ndst) continue;
        int j0 = loff[dl], j1 = loff[dl + 1];

        // inline er[d, head]: dot(hb[dnid[d]], ar) reduced over the 16-lane head group
        int nid = dnid[d];
        unsigned ue = *(const unsigned*)(hbase + (size_t)nid * 256);
        float erv = bflo(ue) * ar0 + bfhi(ue) * ar1;
#pragma unroll
        for (int o = 1; o < 16; o <<= 1) erv += __shfl_xor(erv, o, 64);

        float sumA = 0.f, sumB = 0.f;
        float acc0A = 0.f, acc1A = 0.f, acc0B = 0.f, acc1B = 0.f;
        int j = j0;
        for (; j + 8 <= j1; j += 8) {
            int off[8]; unsigned u[8]; float ev[8];
#pragma unroll
            for (int q = 0; q < 8; ++q) off[q] = ssrc[j + q];
#pragma unroll
            for (int q = 0; q < 8; ++q)
                u[q] = *(const unsigned*)(hbase + off[q]);
#pragma unroll
            for (int q = 0; q < 8; ++q)
                ev[q] = *(const float*)(ebase + (off[q] >> 4));
#pragma unroll
            for (int q = 0; q < 8; ++q) {
                float e = ev[q] + erv;
                e = fmaxf(e, NEG_SLOPE * e);
                float wq = __expf(e);
                if (q & 1) {
                    sumB += wq;
                    acc0B = fmaf(wq, bflo(u[q]), acc0B);
                    acc1B = fmaf(wq, bfhi(u[q]), acc1B);
                } else {
                    sumA += wq;
                    acc0A = fmaf(wq, bflo(u[q]), acc0A);
                    acc1A = fmaf(wq, bfhi(u[q]), acc1A);
                }
            }
        }
        for (; j < j1; ++j) {
            int off0 = ssrc[j];
            unsigned u0 = *(const unsigned*)(hbase + off0);
            float e0 = *(const float*)(ebase + (off0 >> 4)) + erv;
            e0 = fmaxf(e0, NEG_SLOPE * e0);
            float w0 = __expf(e0);
            sumA += w0;
            acc0A = fmaf(w0, bflo(u0), acc0A); acc1A = fmaf(w0, bfhi(u0), acc1A);
        }
        if (cnt > CAP) {                          // never-taken correctness guard
            for (int t = CAP; t < cnt; ++t) {
                int p = ebuf[gbase + t];
                if (((p >> 17) & 31) == dl) {
                    int off0 = (p & 0x1FFFF) << 8;
                    unsigned u0 = *(const unsigned*)(hbase + off0);
                    float e0 = *(const float*)(ebase + (off0 >> 4)) + erv;
                    e0 = fmaxf(e0, NEG_SLOPE * e0);
                    float w0 = __expf(e0);
                    sumA += w0;
                    acc0A = fmaf(w0, bflo(u0), acc0A); acc1A = fmaf(w0, bfhi(u0), acc1A);
                }
            }
        }
        float sum = sumA + sumB;
        bool any = (j1 > j0) || (cnt > CAP);
        float inv = any ? 1.f / sum : 0.f;
        float2 o2 = make_float2((acc0A + acc0B) * inv, (acc1A + acc1B) * inv);
        *(float2*)(out + (size_t)d * HD + 2 * l) = o2;
    }
}

// -----------------------------------------------------------------------------------
extern "C" void kernel_launch(void* const* d_in, const int* in_sizes, int n_in,
                              void* d_out, int out_size, void* d_ws, size_t ws_size,
                              hipStream_t stream)
{
    const float* x   = (const float*)d_in[0];
    const float* fw  = (const float*)d_in[1];
    const float* al  = (const float*)d_in[2];
    const float* ar  = (const float*)d_in[3];
    const int*   src = (const int*)d_in[4];
    const int*   dst = (const int*)d_in[5];
    const int*   dnid= (const int*)d_in[6];
    float* out = (float*)d_out;

    char* ws = (char*)d_ws;
    size_t off = 0;
    auto alloc = [&](size_t bytes) -> void* {
        void* p = ws + off;
        off = (off + bytes + 255) & ~(size_t)255;
        return p;
    };
    short* hb   = (short*)alloc((size_t)N_SRC_N * HD * sizeof(short));   // 25.6 MB
    short* wb   = (short*)alloc((size_t)HD * IN_F * sizeof(short));      // 64 KB
    float* el   = (float*)alloc((size_t)N_SRC_N * NH * sizeof(float));   // 1.6 MB
    int*   ebuf = (int*)alloc((size_t)NE * sizeof(int));                 // 4 MB
    int*   bcnt = (int*)alloc((size_t)NB * sizeof(int));
    int*   boff = (int*)alloc((size_t)NB * sizeof(int));
    int*   bcur = (int*)alloc((size_t)NB * sizeof(int));

    hipMemsetAsync(bcnt, 0, (size_t)NB * sizeof(int), stream);

    cvt_w<<<(HD * IN_F / 4 + 255) / 256, 256, 0, stream>>>(fw, wb);
    gemm_fc_mfma<<<512, 256, 0, stream>>>(x, wb, al, hb, el, (const int4*)dst, bcnt);
    bucket_scan<<<1, 1024, 0, stream>>>(bcnt, boff, bcur, NB);
    partition<<<(NE / 4 + 2047) / 2048, 256, 0, stream>>>((const int4*)src, (const int4*)dst,
                                                          bcur, ebuf, NE / 4);
    gat_gather<<<NB, 256, 0, stream>>>(hb, el, ar, dnid, ebuf, bcnt, boff, out, N_DST_N);
}